// Round 5
// baseline (1163.592 us; speedup 1.0000x reference)
//
#include <hip/hip_runtime.h>
#include <math.h>

#define T_DIM 8192
#define H_DIM 4096
#define I_DIM 11008

typedef int v4i  __attribute__((ext_vector_type(4)));
typedef int v16i __attribute__((ext_vector_type(16)));

#define MFMA8 __builtin_amdgcn_mfma_i32_32x32x32_i8

#define AS1(p) ((const __attribute__((address_space(1))) void*)(p))
#define AS3(p) ((__attribute__((address_space(3))) void*)(p))

#define WAIT_VM_BAR(N) asm volatile("s_waitcnt vmcnt(" #N ")\n\ts_barrier" ::: "memory")
// counted LDS wait + scheduler fence (rule #18)
#define LGKM(N) do { asm volatile("s_waitcnt lgkmcnt(" #N ")" ::: "memory"); \
                     __builtin_amdgcn_sched_barrier(0); } while (0)

__device__ __forceinline__ v4i DSR(const char* p) {
  v4i r;
  unsigned a = (unsigned)(size_t)(const __attribute__((address_space(3))) char*)p;
  asm volatile("ds_read_b128 %0, %1" : "=v"(r) : "v"(a));
  return r;
}

#define STG(buf, src, soff, doff) \
  __builtin_amdgcn_global_load_lds(AS1((src) + (soff)), AS3((buf) + (doff) + dd), 16, 0, 0)

// ---------------- pack + shuffle into MFMA-fragment order (r3/r4-verified) ----
// chunk c (16B): rk=c>>6, lane=c&63; r32=rk/nk32, k32=rk%nk32;
// row = r32*32+(lane&31), k0 = k32*32+(lane>>5)*16.
__global__ void pack_shuf(const int* __restrict__ src, char* __restrict__ dst,
                          int nk32, long nchunk) {
  long c = (long)blockIdx.x * blockDim.x + threadIdx.x;
  long stride = (long)gridDim.x * blockDim.x;
  for (; c < nchunk; c += stride) {
    int lane = (int)(c & 63);
    long rk = c >> 6;
    long r32 = rk / nk32;
    int k32 = (int)(rk - r32 * nk32);
    const int4* s = (const int4*)(src + (r32 * 32 + (lane & 31)) * (long)(nk32 * 32)
                                      + (long)k32 * 32 + ((lane >> 5) << 4));
    int4 a = s[0], b = s[1], cc = s[2], d = s[3];
    int w0 = (a.x & 255) | ((a.y & 255) << 8) | ((a.z & 255) << 16) | (a.w << 24);
    int w1 = (b.x & 255) | ((b.y & 255) << 8) | ((b.z & 255) << 16) | (b.w << 24);
    int w2 = (cc.x & 255) | ((cc.y & 255) << 8) | ((cc.z & 255) << 16) | (cc.w << 24);
    int w3 = (d.x & 255) | ((d.y & 255) << 8) | ((d.z & 255) << 16) | (d.w << 24);
    ((int4*)dst)[c] = make_int4(w0, w1, w2, w3);
  }
}

// ---------------- gate+up fused GEMM: FAT-WAVE ----------------
// 256x128 tile, 4 waves (2M x 2N), 1 wave/SIMD, wave = 128x64 x {gate,up}.
// 16 acc tiles/wave (256 acc regs). Per K=32 step: 8 ds_read_b128 + 16 MFMA.
// Reads for s+1 issued before MFMA(s) cluster -> LDS port works under MFMA.
// LDS: 2x64KB dbuf; per tile, step s: A 8x1KB @ s*16K | G 4x1KB @+8K | U 4x1KB @+12K.
__global__ __launch_bounds__(256, 1) void gemm_gateup(
    const char* __restrict__ A, const char* __restrict__ Bg, const char* __restrict__ Bu,
    const float* __restrict__ ga_p, const float* __restrict__ gb,
    const float* __restrict__ ua_p, const float* __restrict__ ub,
    char* __restrict__ Q)
{
  __shared__ char lds[2][65536];
  const int tid = threadIdx.x;
  const int l = tid & 63;
  const int w = tid >> 6;          // 4 waves
  const int wm = w >> 1, wn = w & 1;
  const int li32 = l & 31, kg2 = l >> 5;

  // XCD-chunked bijection (nwg=2752, %8==0) + 4x2 supertile.
  const int q8 = 2752 / 8;
  int bid = blockIdx.x;
  int wgid = (bid & 7) * q8 + (bid >> 3);
  int st = wgid >> 3, r = wgid & 7;
  int sm = st / 43, sn = st - sm * 43;
  const int m0 = (sm * 4 + (r & 3)) * 256;
  const int n0 = (sn * 2 + (r >> 2)) * 128;

  const int NK = H_DIM / 32;   // 128
  const int NT = H_DIM / 128;  // 32 K-tiles

  v16i accg[4][2], accu[4][2];
#pragma unroll
  for (int i = 0; i < 4; ++i)
#pragma unroll
    for (int n = 0; n < 2; ++n)
#pragma unroll
      for (int j = 0; j < 16; ++j) { accg[i][n][j] = 0; accu[i][n][j] = 0; }

  // DMA source pointers (shuffled [r32][k32][64][16]); each STG = 4KB (4 frags).
  const int tf = tid >> 6, tl = (tid & 63) << 4;
  const char* pA0 = A  + ((size_t)((m0 >> 5) + tf)     * NK << 10) + tl;  // A frags 0-3
  const char* pA1 = A  + ((size_t)((m0 >> 5) + 4 + tf) * NK << 10) + tl;  // A frags 4-7
  const char* pG  = Bg + ((size_t)((n0 >> 5) + tf)     * NK << 10) + tl;  // G frags 0-3
  const char* pU  = Bu + ((size_t)((n0 >> 5) + tf)     * NK << 10) + tl;  // U frags 0-3
  const int dd = tid * 16;

  // Fragment read offsets (lane-linear 1KB fragments).
  const int lo = l * 16;
  const int oA0 = (wm * 4 + 0) * 1024 + lo;
  const int oA1 = (wm * 4 + 1) * 1024 + lo;
  const int oA2 = (wm * 4 + 2) * 1024 + lo;
  const int oA3 = (wm * 4 + 3) * 1024 + lo;
  const int oG0 = 8192  + (wn * 2 + 0) * 1024 + lo;
  const int oG1 = 8192  + (wn * 2 + 1) * 1024 + lo;
  const int oU0 = 12288 + (wn * 2 + 0) * 1024 + lo;
  const int oU1 = 12288 + (wn * 2 + 1) * 1024 + lo;

  v4i E0, E1, E2, E3, Eg0, Eg1, Eu0, Eu1;
  v4i O0, O1, O2, O3, Og0, Og1, Ou0, Ou1;

#define RD_GU(S, B, soff)                                                 \
  do {                                                                    \
    S##0 = DSR((B) + (soff) + oA0);  S##1 = DSR((B) + (soff) + oA1);      \
    S##2 = DSR((B) + (soff) + oA2);  S##3 = DSR((B) + (soff) + oA3);      \
    S##g0 = DSR((B) + (soff) + oG0); S##g1 = DSR((B) + (soff) + oG1);     \
    S##u0 = DSR((B) + (soff) + oU0); S##u1 = DSR((B) + (soff) + oU1);     \
  } while (0)

#define MM_GU(S)                                                          \
  do {                                                                    \
    __builtin_amdgcn_s_setprio(1);                                        \
    accg[0][0] = MFMA8(S##0, S##g0, accg[0][0], 0, 0, 0);                 \
    accg[0][1] = MFMA8(S##0, S##g1, accg[0][1], 0, 0, 0);                 \
    accu[0][0] = MFMA8(S##0, S##u0, accu[0][0], 0, 0, 0);                 \
    accu[0][1] = MFMA8(S##0, S##u1, accu[0][1], 0, 0, 0);                 \
    accg[1][0] = MFMA8(S##1, S##g0, accg[1][0], 0, 0, 0);                 \
    accg[1][1] = MFMA8(S##1, S##g1, accg[1][1], 0, 0, 0);                 \
    accu[1][0] = MFMA8(S##1, S##u0, accu[1][0], 0, 0, 0);                 \
    accu[1][1] = MFMA8(S##1, S##u1, accu[1][1], 0, 0, 0);                 \
    accg[2][0] = MFMA8(S##2, S##g0, accg[2][0], 0, 0, 0);                 \
    accg[2][1] = MFMA8(S##2, S##g1, accg[2][1], 0, 0, 0);                 \
    accu[2][0] = MFMA8(S##2, S##u0, accu[2][0], 0, 0, 0);                 \
    accu[2][1] = MFMA8(S##2, S##u1, accu[2][1], 0, 0, 0);                 \
    accg[3][0] = MFMA8(S##3, S##g0, accg[3][0], 0, 0, 0);                 \
    accg[3][1] = MFMA8(S##3, S##g1, accg[3][1], 0, 0, 0);                 \
    accu[3][0] = MFMA8(S##3, S##u0, accu[3][0], 0, 0, 0);                 \
    accu[3][1] = MFMA8(S##3, S##u1, accu[3][1], 0, 0, 0);                 \
    __builtin_amdgcn_s_setprio(0);                                        \
  } while (0)

  // Stage one K-tile (16 STG calls: 4 per k-step).
#define STAGE_GU(B, kb)                                                   \
  do {                                                                    \
    STG(B, pA0, ((kb) + 0) * 1024, 0);                                    \
    STG(B, pA1, ((kb) + 0) * 1024, 4096);                                 \
    STG(B, pG,  ((kb) + 0) * 1024, 8192);                                 \
    STG(B, pU,  ((kb) + 0) * 1024, 12288);                                \
    STG(B, pA0, ((kb) + 1) * 1024, 16384);                                \
    STG(B, pA1, ((kb) + 1) * 1024, 20480);                                \
    STG(B, pG,  ((kb) + 1) * 1024, 24576);                                \
    STG(B, pU,  ((kb) + 1) * 1024, 28672);                                \
  } while (0)
#define STAGE_GU2(B, kb)                                                  \
  do {                                                                    \
    STG(B, pA0, ((kb) + 2) * 1024, 32768);                                \
    STG(B, pA1, ((kb) + 2) * 1024, 36864);                                \
    STG(B, pG,  ((kb) + 2) * 1024, 40960);                                \
    STG(B, pU,  ((kb) + 2) * 1024, 45056);                                \
    STG(B, pA0, ((kb) + 3) * 1024, 49152);                                \
    STG(B, pA1, ((kb) + 3) * 1024, 53248);                                \
    STG(B, pG,  ((kb) + 3) * 1024, 57344);                                \
    STG(B, pU,  ((kb) + 3) * 1024, 61440);                                \
  } while (0)

  {  // Prologue: stage tile 0, certify, read step-0 fragments.
    char* B0 = lds[0];
    STAGE_GU(B0, 0); STAGE_GU2(B0, 0);
    WAIT_VM_BAR(0);
    RD_GU(E, B0, 0);
  }

  for (int t = 0; t < NT; ++t) {
    char* L  = lds[t & 1];
    char* SB = lds[(t & 1) ^ 1];
    const bool son = (t + 1) < NT;
    const int kb = (t + 1) * 4;

    // P0: read s1; stage next-tile steps 0,1; MFMA(s0)
    RD_GU(O, L, 16384);
    if (son) STAGE_GU(SB, kb);
    LGKM(8);
    MM_GU(E);
    // P1: read s2; stage next-tile steps 2,3; MFMA(s1)
    RD_GU(E, L, 32768);
    if (son) STAGE_GU2(SB, kb);
    LGKM(8);
    MM_GU(O);
    // P2: read s3; MFMA(s2)
    RD_GU(O, L, 49152);
    LGKM(8);
    MM_GU(E);
    // P3: MFMA(s3); boundary; read next tile s0
    LGKM(0);
    MM_GU(O);
    __builtin_amdgcn_sched_barrier(0);
    WAIT_VM_BAR(0);
    if (son) RD_GU(E, SB, 0);
  }
#undef RD_GU
#undef MM_GU
#undef STAGE_GU
#undef STAGE_GU2

  // Epilogue (r4-verified maps): dequant -> SiLU(g)*u -> rint -> clamp -> int8,
  // written in DOWN's shuffled layout [r32][k32=col/32][lane][16B].
  const float ga = *ga_p, ua = *ua_p;
  const int lanehi = ((li32 >> 4) & 1) << 5;
  const int bytelo = li32 & 15;
  const int NKQ = I_DIM / 32;  // 344
#pragma unroll
  for (int ni = 0; ni < 2; ++ni) {
    const int col = n0 + wn * 64 + ni * 32 + li32;
    const float gbv = gb[col], ubv = ub[col];
    const int k32q = (n0 >> 5) + wn * 2 + ni;
#pragma unroll
    for (int mi = 0; mi < 4; ++mi) {
      const int r32q = (m0 >> 5) + wm * 4 + mi;
      char* qbase = Q + ((size_t)(r32q * NKQ + k32q) << 10);
#pragma unroll
      for (int rq = 0; rq < 4; ++rq) {
#pragma unroll
        for (int rr = 0; rr < 4; ++rr) {
          const int rg = rq * 4 + rr;
          const int rowin = kg2 * 4 + rq * 8 + rr;
          float g = (float)accg[mi][ni][rg] * ga + gbv;
          float u = (float)accu[mi][ni][rg] * ua + ubv;
          float x1 = g / (1.0f + expf(-g));
          float x = rintf(x1 * u);
          x = fminf(fmaxf(x, -128.0f), 127.0f);
          qbase[((rowin | lanehi) << 4) + bytelo] = (char)(int)x;
        }
      }
    }
  }
}

// ---------------- down GEMM: FAT-WAVE ----------------
// 256x256 tile, 4 waves (2M x 2N), 1 wave/SIMD, wave = 128x128, acc[4][4].
// Per K=32 step: 8 ds_read_b128 + 16 MFMA. Same rhythm as gateup.
// LDS per tile, step s: A 8x1KB @ s*16K | B 8x1KB @ +8K.
__global__ __launch_bounds__(256, 1) void gemm_down(
    const char* __restrict__ Qm, const char* __restrict__ Bd,
    const float* __restrict__ da_p, const float* __restrict__ db,
    float* __restrict__ out)
{
  __shared__ char lds[2][65536];
  const int tid = threadIdx.x;
  const int l = tid & 63;
  const int w = tid >> 6;
  const int wm = w >> 1, wn = w & 1;
  const int li32 = l & 31, kg2 = l >> 5;

  const int q8 = 512 / 8;
  int bid = blockIdx.x;
  int wgid = (bid & 7) * q8 + (bid >> 3);
  int st = wgid >> 3, r = wgid & 7;
  int sm = st >> 3, sn = st & 7;
  const int m0 = (sm * 4 + (r & 3)) * 256;
  const int n0 = (sn * 2 + (r >> 2)) * 256;

  const int NK = I_DIM / 32;   // 344
  const int NT = I_DIM / 128;  // 86

  v16i acc[4][4];
#pragma unroll
  for (int i = 0; i < 4; ++i)
#pragma unroll
    for (int n = 0; n < 4; ++n)
#pragma unroll
      for (int j = 0; j < 16; ++j) acc[i][n][j] = 0;

  const int tf = tid >> 6, tl = (tid & 63) << 4;
  const char* pA0 = Qm + ((size_t)((m0 >> 5) + tf)     * NK << 10) + tl;
  const char* pA1 = Qm + ((size_t)((m0 >> 5) + 4 + tf) * NK << 10) + tl;
  const char* pB0 = Bd + ((size_t)((n0 >> 5) + tf)     * NK << 10) + tl;
  const char* pB1 = Bd + ((size_t)((n0 >> 5) + 4 + tf) * NK << 10) + tl;
  const int dd = tid * 16;

  const int lo = l * 16;
  const int oA0 = (wm * 4 + 0) * 1024 + lo;
  const int oA1 = (wm * 4 + 1) * 1024 + lo;
  const int oA2 = (wm * 4 + 2) * 1024 + lo;
  const int oA3 = (wm * 4 + 3) * 1024 + lo;
  const int oB0 = 8192 + (wn * 4 + 0) * 1024 + lo;
  const int oB1 = 8192 + (wn * 4 + 1) * 1024 + lo;
  const int oB2 = 8192 + (wn * 4 + 2) * 1024 + lo;
  const int oB3 = 8192 + (wn * 4 + 3) * 1024 + lo;

  v4i E0, E1, E2, E3, Eb0, Eb1, Eb2, Eb3;
  v4i O0, O1, O2, O3, Ob0, Ob1, Ob2, Ob3;

#define RD_DN(S, B, soff)                                                 \
  do {                                                                    \
    S##0 = DSR((B) + (soff) + oA0);  S##1 = DSR((B) + (soff) + oA1);      \
    S##2 = DSR((B) + (soff) + oA2);  S##3 = DSR((B) + (soff) + oA3);      \
    S##b0 = DSR((B) + (soff) + oB0); S##b1 = DSR((B) + (soff) + oB1);     \
    S##b2 = DSR((B) + (soff) + oB2); S##b3 = DSR((B) + (soff) + oB3);     \
  } while (0)

#define MM_DN(S)                                                          \
  do {                                                                    \
    __builtin_amdgcn_s_setprio(1);                                        \
    acc[0][0] = MFMA8(S##0, S##b0, acc[0][0], 0, 0, 0);                   \
    acc[0][1] = MFMA8(S##0, S##b1, acc[0][1], 0, 0, 0);                   \
    acc[0][2] = MFMA8(S##0, S##b2, acc[0][2], 0, 0, 0);                   \
    acc[0][3] = MFMA8(S##0, S##b3, acc[0][3], 0, 0, 0);                   \
    acc[1][0] = MFMA8(S##1, S##b0, acc[1][0], 0, 0, 0);                   \
    acc[1][1] = MFMA8(S##1, S##b1, acc[1][1], 0, 0, 0);                   \
    acc[1][2] = MFMA8(S##1, S##b2, acc[1][2], 0, 0, 0);                   \
    acc[1][3] = MFMA8(S##1, S##b3, acc[1][3], 0, 0, 0);                   \
    acc[2][0] = MFMA8(S##2, S##b0, acc[2][0], 0, 0, 0);                   \
    acc[2][1] = MFMA8(S##2, S##b1, acc[2][1], 0, 0, 0);                   \
    acc[2][2] = MFMA8(S##2, S##b2, acc[2][2], 0, 0, 0);                   \
    acc[2][3] = MFMA8(S##2, S##b3, acc[2][3], 0, 0, 0);                   \
    acc[3][0] = MFMA8(S##3, S##b0, acc[3][0], 0, 0, 0);                   \
    acc[3][1] = MFMA8(S##3, S##b1, acc[3][1], 0, 0, 0);                   \
    acc[3][2] = MFMA8(S##3, S##b2, acc[3][2], 0, 0, 0);                   \
    acc[3][3] = MFMA8(S##3, S##b3, acc[3][3], 0, 0, 0);                   \
    __builtin_amdgcn_s_setprio(0);                                        \
  } while (0)

#define STAGE_DN(B, kb)                                                   \
  do {                                                                    \
    STG(B, pA0, ((kb) + 0) * 1024, 0);                                    \
    STG(B, pA1, ((kb) + 0) * 1024, 4096);                                 \
    STG(B, pB0, ((kb) + 0) * 1024, 8192);                                 \
    STG(B, pB1, ((kb) + 0) * 1024, 12288);                                \
    STG(B, pA0, ((kb) + 1) * 1024, 16384);                                \
    STG(B, pA1, ((kb) + 1) * 1024, 20480);                                \
    STG(B, pB0, ((kb) + 1) * 1024, 24576);                                \
    STG(B, pB1, ((kb) + 1) * 1024, 28672);                                \
  } while (0)
#define STAGE_DN2(B, kb)                                                  \
  do {                                                                    \
    STG(B, pA0, ((kb) + 2) * 1024, 32768);                                \
    STG(B, pA1, ((kb) + 2) * 1024, 36864);                                \
    STG(B, pB0, ((kb) + 2) * 1024, 40960);                                \
    STG(B, pB1, ((kb) + 2) * 1024, 45056);                                \
    STG(B, pA0, ((kb) + 3) * 1024, 49152);                                \
    STG(B, pA1, ((kb) + 3) * 1024, 53248);                                \
    STG(B, pB0, ((kb) + 3) * 1024, 57344);                                \
    STG(B, pB1, ((kb) + 3) * 1024, 61440);                                \
  } while (0)

  {
    char* B0 = lds[0];
    STAGE_DN(B0, 0); STAGE_DN2(B0, 0);
    WAIT_VM_BAR(0);
    RD_DN(E, B0, 0);
  }

  for (int t = 0; t < NT; ++t) {
    char* L  = lds[t & 1];
    char* SB = lds[(t & 1) ^ 1];
    const bool son = (t + 1) < NT;
    const int kb = (t + 1) * 4;

    RD_DN(O, L, 16384);
    if (son) STAGE_DN(SB, kb);
    LGKM(8);
    MM_DN(E);

    RD_DN(E, L, 32768);
    if (son) STAGE_DN2(SB, kb);
    LGKM(8);
    MM_DN(O);

    RD_DN(O, L, 49152);
    LGKM(8);
    MM_DN(E);

    LGKM(0);
    MM_DN(O);
    __builtin_amdgcn_sched_barrier(0);
    WAIT_VM_BAR(0);
    if (son) RD_DN(E, SB, 0);
  }
#undef RD_DN
#undef MM_DN
#undef STAGE_DN
#undef STAGE_DN2

  const float da = *da_p;
#pragma unroll
  for (int ni = 0; ni < 4; ++ni) {
    const int col = n0 + wn * 128 + ni * 32 + li32;
    const float dbv = db[col];
#pragma unroll
    for (int mi = 0; mi < 4; ++mi) {
      const int rowb = m0 + wm * 128 + mi * 32 + kg2 * 4;
#pragma unroll
      for (int rq = 0; rq < 4; ++rq) {
#pragma unroll
        for (int rr = 0; rr < 4; ++rr)
          out[(size_t)(rowb + rq * 8 + rr) * H_DIM + col] =
              (float)acc[mi][ni][rq * 4 + rr] * da + dbv;
      }
    }
  }
}

extern "C" void kernel_launch(void* const* d_in, const int* in_sizes, int n_in,
                              void* d_out, int out_size, void* d_ws, size_t ws_size,
                              hipStream_t stream) {
  const int*   hs = (const int*)d_in[0];
  const int*   gw = (const int*)d_in[1];
  const float* ga = (const float*)d_in[2];
  const float* gb = (const float*)d_in[3];
  const int*   uw = (const int*)d_in[4];
  const float* ua = (const float*)d_in[5];
  const float* ub = (const float*)d_in[6];
  const int*   dw = (const int*)d_in[7];
  const float* da = (const float*)d_in[8];
  const float* db = (const float*)d_in[9];

  char* ws   = (char*)d_ws;
  char* hidS = ws;                                  // [256][128][64][16] shuffled
  char* gS   = hidS + (size_t)T_DIM * H_DIM;        // [344][128][64][16]
  char* uS   = gS   + (size_t)I_DIM * H_DIM;
  char* dS   = uS   + (size_t)I_DIM * H_DIM;        // [128][344][64][16]
  char* qS   = dS   + (size_t)H_DIM * I_DIM;        // [256][344][64][16]

  pack_shuf<<<2048, 256, 0, stream>>>(hs, hidS, H_DIM / 32, (long)T_DIM * H_DIM / 16);
  pack_shuf<<<2048, 256, 0, stream>>>(gw, gS,   H_DIM / 32, (long)I_DIM * H_DIM / 16);
  pack_shuf<<<2048, 256, 0, stream>>>(uw, uS,   H_DIM / 32, (long)I_DIM * H_DIM / 16);
  pack_shuf<<<2048, 256, 0, stream>>>(dw, dS,   I_DIM / 32, (long)H_DIM * I_DIM / 16);

  gemm_gateup<<<2752, 256, 0, stream>>>(hidS, gS, uS, ga, gb, ua, ub, qS);
  gemm_down<<<512, 256, 0, stream>>>(qS, dS, da, db, (float*)d_out);
}

// Round 7
// 1089.298 us; speedup vs baseline: 1.0682x; 1.0682x over previous
//
#include <hip/hip_runtime.h>
#include <math.h>

#define T_DIM 8192
#define H_DIM 4096
#define I_DIM 11008

typedef int v4i  __attribute__((ext_vector_type(4)));
typedef int v16i __attribute__((ext_vector_type(16)));

#define MFMA8 __builtin_amdgcn_mfma_i32_32x32x32_i8

#define AS1(p) ((const __attribute__((address_space(1))) void*)(p))
#define AS3(p) ((__attribute__((address_space(3))) void*)(p))

// counted vmcnt wait (NEVER 0 in the steady loop) + scheduler fence
#define WAITV(N) do { asm volatile("s_waitcnt vmcnt(" #N ")" ::: "memory"); \
                      __builtin_amdgcn_sched_barrier(0); } while (0)
#define BAR() __builtin_amdgcn_s_barrier()
// counted LDS wait + scheduler fence (rule #18)
#define LGKM(N) do { asm volatile("s_waitcnt lgkmcnt(" #N ")" ::: "memory"); \
                     __builtin_amdgcn_sched_barrier(0); } while (0)

__device__ __forceinline__ v4i DSR(const char* p) {
  v4i r;
  unsigned a = (unsigned)(size_t)(const __attribute__((address_space(3))) char*)p;
  asm volatile("ds_read_b128 %0, %1" : "=v"(r) : "v"(a));
  return r;
}

// One STG = one whole 1KB fragment per wave: LDS dest = wave-uniform base +
// lane*16 (m104 rule), global src lane-linear.
#define STG(ldst, gsrc) \
  __builtin_amdgcn_global_load_lds(AS1(gsrc), AS3(ldst), 16, 0, 0)

// ---------------- pack + shuffle into MFMA-fragment order (r3/r4-verified) ----
__global__ void pack_shuf(const int* __restrict__ src, char* __restrict__ dst,
                          int nk32, long nchunk) {
  long c = (long)blockIdx.x * blockDim.x + threadIdx.x;
  long stride = (long)gridDim.x * blockDim.x;
  for (; c < nchunk; c += stride) {
    int lane = (int)(c & 63);
    long rk = c >> 6;
    long r32 = rk / nk32;
    int k32 = (int)(rk - r32 * nk32);
    const int4* s = (const int4*)(src + (r32 * 32 + (lane & 31)) * (long)(nk32 * 32)
                                      + (long)k32 * 32 + ((lane >> 5) << 4));
    int4 a = s[0], b = s[1], cc = s[2], d = s[3];
    int w0 = (a.x & 255) | ((a.y & 255) << 8) | ((a.z & 255) << 16) | (a.w << 24);
    int w1 = (b.x & 255) | ((b.y & 255) << 8) | ((b.z & 255) << 16) | (b.w << 24);
    int w2 = (cc.x & 255) | ((cc.y & 255) << 8) | ((cc.z & 255) << 16) | (cc.w << 24);
    int w3 = (d.x & 255) | ((d.y & 255) << 8) | ((d.z & 255) << 16) | (d.w << 24);
    ((int4*)dst)[c] = make_int4(w0, w1, w2, w3);
  }
}

// ---------------- gate+up fused GEMM ----------------
// 256x128 tile, 8 waves (2M x 4N), wave = 128x32 x {gate,up}, BK=64.
// 3x32KB LDS bufs, stage distance 2, counted vmcnt(4) certification.
// ALWAYS stage 4 loads/tile (tail clamped to NT-1, lands in a never-read buf)
// so the per-wave vmcnt ledger is uniform: 8 outstanding at P1 -> WAITV(4)
// retires exactly the next tile's 4 loads, every iteration incl. tail.
__global__ __launch_bounds__(512, 2) void gemm_gateup(
    const char* __restrict__ A, const char* __restrict__ Bg, const char* __restrict__ Bu,
    const float* __restrict__ ga_p, const float* __restrict__ gb,
    const float* __restrict__ ua_p, const float* __restrict__ ub,
    char* __restrict__ Q)
{
  __shared__ char lds[3][32768];
  const int tid = threadIdx.x;
  const int l = tid & 63;
  const int w = tid >> 6;          // 8 waves
  const int wm = w >> 2, wn = w & 3;
  const int li32 = l & 31, kg2 = l >> 5;

  // XCD-chunked bijection (nwg=2752, %8==0) + 4x2 supertile.
  const int q8 = 2752 / 8;
  int bid = blockIdx.x;
  int wgid = (bid & 7) * q8 + (bid >> 3);
  int st = wgid >> 3, r = wgid & 7;
  int sm = st / 43, sn = st - sm * 43;
  const int m0 = (sm * 4 + (r & 3)) * 256;
  const int n0 = (sn * 2 + (r >> 2)) * 128;

  const int NK = H_DIM / 32;   // 128 k32 blocks
  const int NT = H_DIM / 64;   // 64 K-tiles (BK=64)

  v16i accg[4], accu[4];
#pragma unroll
  for (int i = 0; i < 4; ++i)
#pragma unroll
    for (int j = 0; j < 16; ++j) { accg[i][j] = 0; accu[i][j] = 0; }

  // Wave-fragment staging: wave w stages A frags (r32=w, ks=0/1), G frag
  // (n32=w>>1, ks=w&1), U frag (same). Src advances by 2048 per tile.
  const int lo = l * 16;
  const char* pA0 = A  + ((size_t)((m0 >> 5) + w) * NK + 0) * 1024 + lo;
  const char* pA1 = A  + ((size_t)((m0 >> 5) + w) * NK + 1) * 1024 + lo;
  const char* pG  = Bg + ((size_t)((n0 >> 5) + (w >> 1)) * NK + (w & 1)) * 1024 + lo;
  const char* pU  = Bu + ((size_t)((n0 >> 5) + (w >> 1)) * NK + (w & 1)) * 1024 + lo;
  const int dA0 = w * 2048 + lo;
  const int dA1 = dA0 + 1024;
  const int dG  = 16384 + w * 1024 + lo;
  const int dU  = dG + 8192;

#define STAGE_GU(SB, tt)                                                  \
  do {                                                                    \
    size_t so = (size_t)(tt) * 2048;                                      \
    STG((SB) + dA0, pA0 + so);                                            \
    STG((SB) + dA1, pA1 + so);                                            \
    STG((SB) + dG,  pG  + so);                                            \
    STG((SB) + dU,  pU  + so);                                            \
  } while (0)

  const int oA0 = (wm * 4 + 0) * 2048 + lo;
  const int oA1 = (wm * 4 + 1) * 2048 + lo;
  const int oA2 = (wm * 4 + 2) * 2048 + lo;
  const int oA3 = (wm * 4 + 3) * 2048 + lo;
  const int oG  = 16384 + wn * 2048 + lo;
  const int oU  = 24576 + wn * 2048 + lo;

  v4i E0, E1, E2, E3, Eg, Eu;
  v4i O0, O1, O2, O3, Og, Ou;

#define RD_GU(S, B, s)                                                    \
  do {                                                                    \
    S##0 = DSR((B) + oA0 + (s) * 1024);                                   \
    S##1 = DSR((B) + oA1 + (s) * 1024);                                   \
    S##2 = DSR((B) + oA2 + (s) * 1024);                                   \
    S##3 = DSR((B) + oA3 + (s) * 1024);                                   \
    S##g = DSR((B) + oG  + (s) * 1024);                                   \
    S##u = DSR((B) + oU  + (s) * 1024);                                   \
  } while (0)

#define MM_GU(S)                                                          \
  do {                                                                    \
    __builtin_amdgcn_s_setprio(1);                                        \
    accg[0] = MFMA8(S##0, S##g, accg[0], 0, 0, 0);                        \
    accu[0] = MFMA8(S##0, S##u, accu[0], 0, 0, 0);                        \
    accg[1] = MFMA8(S##1, S##g, accg[1], 0, 0, 0);                        \
    accu[1] = MFMA8(S##1, S##u, accu[1], 0, 0, 0);                        \
    accg[2] = MFMA8(S##2, S##g, accg[2], 0, 0, 0);                        \
    accu[2] = MFMA8(S##2, S##u, accu[2], 0, 0, 0);                        \
    accg[3] = MFMA8(S##3, S##g, accg[3], 0, 0, 0);                        \
    accu[3] = MFMA8(S##3, S##u, accu[3], 0, 0, 0);                        \
    __builtin_amdgcn_s_setprio(0);                                        \
  } while (0)

  char* b0 = lds[0];
  char* b1 = lds[1];
  char* b2 = lds[2];

  {  // Prologue: stage tiles 0,1; certify tile 0 via counted vmcnt(4).
    STAGE_GU(b0, 0);
    STAGE_GU(b1, 1);
    WAITV(4);
    BAR();
    RD_GU(E, b0, 0);
  }

  for (int t = 0; t < NT; ++t) {
    const int tstage = (t + 2 < NT) ? (t + 2) : (NT - 1);  // tail-clamped dup
    // P0: read s1 of current; stage (clamped) tile t+2; MFMA(s0)
    RD_GU(O, b0, 1);
    STAGE_GU(b2, tstage);
    LGKM(6);
    MM_GU(E);
    // P1: certify buf(t+1) via counted wait (always exactly 8 outstanding:
    // 4 for t+1 issued last iter + 4 for t+2 issued this iter).
    WAITV(4);
    BAR();
    if (t + 1 < NT) {
      RD_GU(E, b1, 0);
      LGKM(6);
    } else {
      LGKM(0);
    }
    MM_GU(O);
    char* tmp = b0; b0 = b1; b1 = b2; b2 = tmp;
  }
  WAITV(0);   // drain leftover tail DMAs before epilogue/end
#undef RD_GU
#undef MM_GU
#undef STAGE_GU

  // Epilogue (r4-verified): dequant -> SiLU(g)*u -> rint -> clamp -> int8,
  // written in DOWN's shuffled layout [r32][k32=col/32][lane][16B].
  const float ga = *ga_p, ua = *ua_p;
  const int col = n0 + wn * 32 + li32;
  const float gbv = gb[col], ubv = ub[col];
  const int k32q = (n0 >> 5) + wn;
  const int lanehi = ((li32 >> 4) & 1) << 5;
  const int bytelo = li32 & 15;
  const int NKQ = I_DIM / 32;  // 344
#pragma unroll
  for (int mi = 0; mi < 4; ++mi) {
    const int r32q = (m0 >> 5) + wm * 4 + mi;
    char* qbase = Q + ((size_t)(r32q * NKQ + k32q) << 10);
#pragma unroll
    for (int rq = 0; rq < 4; ++rq) {
#pragma unroll
      for (int rr = 0; rr < 4; ++rr) {
        const int rg = rq * 4 + rr;
        const int rowin = kg2 * 4 + rq * 8 + rr;
        float g = (float)accg[mi][rg] * ga + gbv;
        float u = (float)accu[mi][rg] * ua + ubv;
        float x1 = g / (1.0f + expf(-g));
        float x = rintf(x1 * u);
        x = fminf(fmaxf(x, -128.0f), 127.0f);
        qbase[((rowin | lanehi) << 4) + bytelo] = (char)(int)x;
      }
    }
  }
}

// ---------------- down GEMM ----------------
// 256x256 tile, 8 waves (2M x 4N), wave = 128x64, BK=64, 3x32KB bufs,
// stage distance 2, counted vmcnt(4), tail-clamped staging.
__global__ __launch_bounds__(512, 2) void gemm_down(
    const char* __restrict__ Qm, const char* __restrict__ Bd,
    const float* __restrict__ da_p, const float* __restrict__ db,
    float* __restrict__ out)
{
  __shared__ char lds[3][32768];
  const int tid = threadIdx.x;
  const int l = tid & 63;
  const int w = tid >> 6;
  const int wm = w >> 2, wn = w & 3;
  const int li32 = l & 31, kg2 = l >> 5;

  const int q8 = 512 / 8;
  int bid = blockIdx.x;
  int wgid = (bid & 7) * q8 + (bid >> 3);
  int st = wgid >> 3, r = wgid & 7;
  int sm = st >> 3, sn = st & 7;
  const int m0 = (sm * 4 + (r & 3)) * 256;
  const int n0 = (sn * 2 + (r >> 2)) * 256;

  const int NK = I_DIM / 32;   // 344
  const int NT = I_DIM / 64;   // 172 K-tiles

  v16i acc[4][2];
#pragma unroll
  for (int i = 0; i < 4; ++i)
#pragma unroll
    for (int n = 0; n < 2; ++n)
#pragma unroll
      for (int j = 0; j < 16; ++j) acc[i][n][j] = 0;

  const int lo = l * 16;
  const char* pA0 = Qm + ((size_t)((m0 >> 5) + w) * NK + 0) * 1024 + lo;
  const char* pA1 = Qm + ((size_t)((m0 >> 5) + w) * NK + 1) * 1024 + lo;
  const char* pB0 = Bd + ((size_t)((n0 >> 5) + w) * NK + 0) * 1024 + lo;
  const char* pB1 = Bd + ((size_t)((n0 >> 5) + w) * NK + 1) * 1024 + lo;
  const int dA0 = w * 2048 + lo;
  const int dA1 = dA0 + 1024;
  const int dB0 = 16384 + w * 2048 + lo;
  const int dB1 = dB0 + 1024;

#define STAGE_DN(SB, tt)                                                  \
  do {                                                                    \
    size_t so = (size_t)(tt) * 2048;                                      \
    STG((SB) + dA0, pA0 + so);                                            \
    STG((SB) + dA1, pA1 + so);                                            \
    STG((SB) + dB0, pB0 + so);                                            \
    STG((SB) + dB1, pB1 + so);                                            \
  } while (0)

  const int oA0 = (wm * 4 + 0) * 2048 + lo;
  const int oA1 = (wm * 4 + 1) * 2048 + lo;
  const int oA2 = (wm * 4 + 2) * 2048 + lo;
  const int oA3 = (wm * 4 + 3) * 2048 + lo;
  const int oB0 = 16384 + (wn * 2 + 0) * 2048 + lo;
  const int oB1 = 16384 + (wn * 2 + 1) * 2048 + lo;

  v4i E0, E1, E2, E3, Eb0, Eb1;
  v4i O0, O1, O2, O3, Ob0, Ob1;

#define RD_DN(S, B, s)                                                    \
  do {                                                                    \
    S##0 = DSR((B) + oA0 + (s) * 1024);                                   \
    S##1 = DSR((B) + oA1 + (s) * 1024);                                   \
    S##2 = DSR((B) + oA2 + (s) * 1024);                                   \
    S##3 = DSR((B) + oA3 + (s) * 1024);                                   \
    S##b0 = DSR((B) + oB0 + (s) * 1024);                                  \
    S##b1 = DSR((B) + oB1 + (s) * 1024);                                  \
  } while (0)

#define MM_DN(S)                                                          \
  do {                                                                    \
    __builtin_amdgcn_s_setprio(1);                                        \
    acc[0][0] = MFMA8(S##0, S##b0, acc[0][0], 0, 0, 0);                   \
    acc[0][1] = MFMA8(S##0, S##b1, acc[0][1], 0, 0, 0);                   \
    acc[1][0] = MFMA8(S##1, S##b0, acc[1][0], 0, 0, 0);                   \
    acc[1][1] = MFMA8(S##1, S##b1, acc[1][1], 0, 0, 0);                   \
    acc[2][0] = MFMA8(S##2, S##b0, acc[2][0], 0, 0, 0);                   \
    acc[2][1] = MFMA8(S##2, S##b1, acc[2][1], 0, 0, 0);                   \
    acc[3][0] = MFMA8(S##3, S##b0, acc[3][0], 0, 0, 0);                   \
    acc[3][1] = MFMA8(S##3, S##b1, acc[3][1], 0, 0, 0);                   \
    __builtin_amdgcn_s_setprio(0);                                        \
  } while (0)

  char* b0 = lds[0];
  char* b1 = lds[1];
  char* b2 = lds[2];

  {
    STAGE_DN(b0, 0);
    STAGE_DN(b1, 1);
    WAITV(4);
    BAR();
    RD_DN(E, b0, 0);
  }

  for (int t = 0; t < NT; ++t) {
    const int tstage = (t + 2 < NT) ? (t + 2) : (NT - 1);
    RD_DN(O, b0, 1);
    STAGE_DN(b2, tstage);
    LGKM(6);
    MM_DN(E);

    WAITV(4);
    BAR();
    if (t + 1 < NT) {
      RD_DN(E, b1, 0);
      LGKM(6);
    } else {
      LGKM(0);
    }
    MM_DN(O);

    char* tmp = b0; b0 = b1; b1 = b2; b2 = tmp;
  }
  WAITV(0);
#undef RD_DN
#undef MM_DN
#undef STAGE_DN

  const float da = *da_p;
#pragma unroll
  for (int ni = 0; ni < 2; ++ni) {
    const int col = n0 + wn * 64 + ni * 32 + li32;
    const float dbv = db[col];
#pragma unroll
    for (int mi = 0; mi < 4; ++mi) {
      const int rowb = m0 + wm * 128 + mi * 32 + kg2 * 4;
#pragma unroll
      for (int rq = 0; rq < 4; ++rq) {
#pragma unroll
        for (int rr = 0; rr < 4; ++rr)
          out[(size_t)(rowb + rq * 8 + rr) * H_DIM + col] =
              (float)acc[mi][ni][rq * 4 + rr] * da + dbv;
      }
    }
  }
}

extern "C" void kernel_launch(void* const* d_in, const int* in_sizes, int n_in,
                              void* d_out, int out_size, void* d_ws, size_t ws_size,
                              hipStream_t stream) {
  const int*   hs = (const int*)d_in[0];
  const int*   gw = (const int*)d_in[1];
  const float* ga = (const float*)d_in[2];
  const float* gb = (const float*)d_in[3];
  const int*   uw = (const int*)d_in[4];
  const float* ua = (const float*)d_in[5];
  const float* ub = (const float*)d_in[6];
  const int*   dw = (const int*)d_in[7];
  const float* da = (const float*)d_in[8];
  const float* db = (const float*)d_in[9];

  char* ws   = (char*)d_ws;
  char* hidS = ws;                                  // [256][128][64][16] shuffled
  char* gS   = hidS + (size_t)T_DIM * H_DIM;        // [344][128][64][16]
  char* uS   = gS   + (size_t)I_DIM * H_DIM;
  char* dS   = uS   + (size_t)I_DIM * H_DIM;        // [128][344][64][16]
  char* qS   = dS   + (size_t)H_DIM * I_DIM;        // [256][344][64][16]

  pack_shuf<<<2048, 256, 0, stream>>>(hs, hidS, H_DIM / 32, (long)T_DIM * H_DIM / 16);
  pack_shuf<<<2048, 256, 0, stream>>>(gw, gS,   H_DIM / 32, (long)I_DIM * H_DIM / 16);
  pack_shuf<<<2048, 256, 0, stream>>>(uw, uS,   H_DIM / 32, (long)I_DIM * H_DIM / 16);
  pack_shuf<<<2048, 256, 0, stream>>>(dw, dS,   I_DIM / 32, (long)H_DIM * I_DIM / 16);

  gemm_gateup<<<2752, 512, 0, stream>>>(hidS, gS, uS, ga, gb, ua, ub, qS);
  gemm_down<<<512, 512, 0, stream>>>(qS, dS, da, db, (float*)d_out);
}